// Round 8
// baseline (2823.843 us; speedup 1.0000x reference)
//
#include <hip/hip_runtime.h>

// LSTM last-h + LeakyReLU(0.3). B=128 T=1024 F=64 H=256.
// R25: R24 (MFMA-pipe dots) with the correctness bugs fixed.
// R24 post-mortem (absmax 0.457): A0/A1/Bp LDS pointers were __restrict__
// while xh is rewritten every step through xh[][][] lvalues -> UB; the
// compiler may cache the A-fragment ds_reads across steps (even across
// __syncthreads) -> MFMA consumed stale x/h; tanh/sigmoid bounding makes
// that a moderate bounded error, exactly as observed. Also hardened:
//  - post-MFMA guard now CARRIES acc ("+v"(acc) on the s_nop asm) +
//    sched_barrier(0): without the dependency the compiler could place
//    the acc-reading VALU between the last MFMA and the nops (rule #18).
//  - "s_nop 1" with acc dependency between acc zero-init (VALU) and the
//    first MFMA read of SrcC (VALU->MFMA hazard, manual for inline asm).
// Structure (R24): per WG per step z[2x256] = xh[2x320] @ W[320x256] via
// 10 chained v_mfma_f32_16x16x32_f16 per wave (16-col tile, K=320).
//  - col c=4j+g: 4 gates of h-col j in one wave's D frag -> in-wave gates.
//  - B chunks 0-3 in LDS (64KB); chunks 4-9 pinned in AGPRs ("a").
//  - 2 barriers/step; R17-proven tagged-uint64 exchange skeleton.

#define BATCH   128
#define TSTEPS  1024
#define FDIM    64
#define HDIM    256
#define G4      1024
#define NCHUNK  10
#define W4S_U4     (4 * NCHUNK * 1024)           // 40960 uint4
#define W4S_BYTES  (W4S_U4 * 16)                 // 655360
#define EX_OFF     W4S_BYTES
#define EX_SLOTS   (64 * 4 * 2 * 2 * 32)         // 32768 uint64 slots
#define EX_BYTES   (EX_SLOTS * 8)                // 262144
#define WS_NEED    (EX_OFF + EX_BYTES)           // 917504 (unchanged)

typedef unsigned u32x4 __attribute__((ext_vector_type(4)));
typedef float    f32x4 __attribute__((ext_vector_type(4)));

__device__ __forceinline__ unsigned pack2(float a, float b) {
    union { _Float16 h[2]; unsigned u; } c;
    c.h[0] = (_Float16)a; c.h[1] = (_Float16)b; return c.u;
}

// B-fragment pack: w4s[cg][c][w][l] (uint4) holds B[k,col] f16 pairs with
// col = 16w + (l&15) -> (j = 4w + ((l&15)>>2), g = l&3), gcol = g*256+cg*64+j
// k = c*32 + ((l>>4)&3)*8 + 2d + s2   (matrix-core B layout, 16x16x32)
__global__ void pack_mfma(const float* __restrict__ wk,
                          const float* __restrict__ wr,
                          unsigned* __restrict__ w4s) {
    int idx = blockIdx.x * blockDim.x + threadIdx.x;
    if (idx >= W4S_U4 * 4) return;
    int u4 = idx >> 2, d = idx & 3;
    int l  = u4 & 63;
    int w  = (u4 >> 6) & 15;
    int c  = (u4 >> 10) % NCHUNK;
    int cg = u4 / (NCHUNK * 1024);
    int j  = 4 * w + ((l & 15) >> 2);
    int g  = l & 3;
    int gcol = g * 256 + cg * 64 + j;
    int kb = c * 32 + ((l >> 4) & 3) * 8 + 2 * d;
    float v[2];
    #pragma unroll
    for (int s2 = 0; s2 < 2; ++s2) {
        int kp = kb + s2;
        float val;
        if (kp < 64)       val = wk[kp * G4 + gcol];
        else if (kp < 128) val = wr[(cg * 64 + (kp - 64)) * G4 + gcol];
        else {
            int m = 1 + ((kp - 128) >> 6);
            val = wr[(((cg + m) & 3) * 64 + ((kp - 128) & 63)) * G4 + gcol];
        }
        v[s2] = val;
    }
    w4s[idx] = pack2(v[0], v[1]);
}

#define MFMA_LDS(c) do { \
    u32x4 av_ = Apl[4 * (c)]; \
    u32x4 bv_ = Bp[(c) << 10]; \
    asm volatile("v_mfma_f32_16x16x32_f16 %0, %1, %2, %0" \
                 : "+v"(acc) : "v"(av_), "v"(bv_)); } while (0)

#define MFMA_REG(c, W) do { \
    u32x4 av_ = Apl[4 * (c)]; \
    asm volatile("v_mfma_f32_16x16x32_f16 %0, %1, %2, %0" \
                 : "+v"(acc) : "v"(av_), "a"(W)); } while (0)

__global__ __launch_bounds__(1024) void lstm_mfma(
    const float* __restrict__ inputs,
    const unsigned* __restrict__ w4s,
    const float* __restrict__ bias,
    unsigned long long* __restrict__ ex2,
    float* __restrict__ out)
{
    __shared__ u32x4 ldsB[4 * 1024];                    // 64 KB: B chunks 0-3
    __shared__ __align__(16) unsigned xh[2][2][160];    // 2.5 KB

    const int bid = blockIdx.x;
    const int pg  = bid & 63;                  // batch rows 2pg, 2pg+1
    const int cg  = bid >> 6;                  // col-group 0..3
    const int tid = threadIdx.x;
    const int l   = tid & 63;
    const int w   = tid >> 6;

    const u32x4* __restrict__ Wcg = (const u32x4*)w4s + (size_t)cg * (NCHUNK * 1024);

    // LDS fill: B chunks 0-3 (linear copy; layout already fragment-packed)
    for (int i = tid; i < 4 * 1024; i += 1024) ldsB[i] = Wcg[i];

    // B chunks 4-9 -> AGPRs (24 regs), loaded once, pinned in "a" class
    u32x4 Wr0 = Wcg[4 * 1024 + tid]; asm volatile("" : "+a"(Wr0));
    u32x4 Wr1 = Wcg[5 * 1024 + tid]; asm volatile("" : "+a"(Wr1));
    u32x4 Wr2 = Wcg[6 * 1024 + tid]; asm volatile("" : "+a"(Wr2));
    u32x4 Wr3 = Wcg[7 * 1024 + tid]; asm volatile("" : "+a"(Wr3));
    u32x4 Wr4 = Wcg[8 * 1024 + tid]; asm volatile("" : "+a"(Wr4));
    u32x4 Wr5 = Wcg[9 * 1024 + tid]; asm volatile("" : "+a"(Wr5));

    const float* __restrict__ xr0 = inputs + (size_t)(2 * pg)     * TSTEPS * FDIM;
    const float* __restrict__ xr1 = inputs + (size_t)(2 * pg + 1) * TSTEPS * FDIM;

    // init xh[0]: dw 0..31 = x_0 (f16 pairs), 32..159 = h_0 = 0
    if (tid < 64) {
        int r = tid >> 5, dd = tid & 31;
        float2 x2 = ((const float2*)(r ? xr1 : xr0))[dd];
        xh[0][r][dd] = pack2(x2.x, x2.y);
    } else if (tid < 320) {
        int t2 = tid - 64;
        xh[0][t2 >> 7][32 + (t2 & 127)] = 0u;
    }

    // gate identity per lane (lanes 0..15 meaningful)
    const int  jj  = 4 * w + ((l & 15) >> 2);
    const int  g   = l & 3;
    const float bsv = bias[g * 256 + cg * 64 + jj];
    const bool isC  = (g == 2);                 // c-gate uses tanh

    // A-fragment bases (NO restrict: xh is rewritten through xh[][][]).
    // row = l&1 (rows 2-15 fed duplicates; their D rows unread),
    // kgroup = l>>4.
    const char* xb = (const char*)&xh[0][0][0];
    const u32x4* A0 =
        (const u32x4*)(xb + ((l & 1) * 160) * 4 + ((l >> 4) & 3) * 16);
    const u32x4* A1 =
        (const u32x4*)(xb + ((2 + (l & 1)) * 160) * 4 + ((l >> 4) & 3) * 16);
    const u32x4* Bp = ldsB + tid;               // NO restrict

    // gather: lanes 16..27 of every wave (16*12 = 192 = 3 partners x 64)
    const int  gl   = (l >= 16 && l < 28) ? (l - 16) : 0;
    const int  gidx = w * 12 + gl;
    const int  mi   = gidx >> 6, wi_ = gidx & 63;
    const int  grr  = wi_ >> 5, gdw = wi_ & 31;
    const int  cgp  = (cg + mi + 1) & 3;
    unsigned long long* const srcE =
        ex2 + ((size_t)((pg * 4 + cgp) * 2 + 0) * 2 + grr) * 32 + gdw;
    unsigned long long* const srcO =
        ex2 + ((size_t)((pg * 4 + cgp) * 2 + 1) * 2 + grr) * 32 + gdw;
    unsigned* const dstE = &xh[0][grr][64 + mi * 32 + gdw];
    unsigned* const dstO = &xh[1][grr][64 + mi * 32 + gdw];

    // stagers: lanes 28..31 of every wave (16*4 = 64 = 2 rows x 32 dwords)
    const int  sl  = (l >= 28 && l < 32) ? (l - 28) : 0;
    const int  sx  = w * 4 + sl;
    const int  srr = sx >> 5, sdd = sx & 31;
    const float2* __restrict__ xsp = (const float2*)(srr ? xr1 : xr0) + sdd;

    float cst0 = 0.0f, cst1 = 0.0f;
    __syncthreads();

    for (int s = 0; s < TSTEPS; ++s) {
        const int par = s & 1, ncp = par ^ 1;
        const u32x4* Apl = par ? A1 : A0;

        // speculative poll issue (flies under chunks 0-3)
        const bool gath = (l >= 16) && (l < 28) && (s > 0);
        unsigned long long* const gsrc = par ? srcO : srcE;
        unsigned long long pv = 0;
        if (gath) pv = __hip_atomic_load(gsrc, __ATOMIC_RELAXED,
                                         __HIP_MEMORY_SCOPE_AGENT);

        // x_{s+1} prefetch
        const bool stg = (l >= 28) && (l < 32) && (s + 1 < TSTEPS);
        float2 xnext = make_float2(0.f, 0.f);
        if (stg) xnext = xsp[(s + 1) * 32];

        f32x4 acc = {0.0f, 0.0f, 0.0f, 0.0f};
        // VALU write -> MFMA SrcC hazard guard (inline-asm MFMAs get no
        // automatic hazard handling), and pins init before the cluster.
        asm volatile("s_nop 1" : "+v"(acc));

        // chunks 0-3: x + own-h (B from LDS)
        MFMA_LDS(0); MFMA_LDS(1); MFMA_LDS(2); MFMA_LDS(3);

        // gather completion after own-work: B1 at max(D_early, RTT-rem)
        if (gath) {
            int it = 0;
            while ((unsigned)(pv >> 32) != (unsigned)s && ++it < (1 << 22))
                pv = __hip_atomic_load(gsrc, __ATOMIC_RELAXED,
                                       __HIP_MEMORY_SCOPE_AGENT);
            unsigned gv = ((unsigned)(pv >> 32) == (unsigned)s) ? (unsigned)pv : 0u;
            *(par ? dstO : dstE) = gv;
        }
        __syncthreads();                                   // B1

        // chunks 4-9: partner-h (B from AGPR)
        MFMA_REG(4, Wr0); MFMA_REG(5, Wr1); MFMA_REG(6, Wr2);
        MFMA_REG(7, Wr3); MFMA_REG(8, Wr4); MFMA_REG(9, Wr5);

        // SW hazard guard: MFMA -> VALU/ds_bpermute reads of acc.
        // The "+v"(acc) dependency forces every subsequent acc read to
        // sit AFTER these nops; sched_barrier pins the region.
        asm volatile("s_nop 7\n\ts_nop 7\n\ts_nop 7" : "+v"(acc));
        __builtin_amdgcn_sched_barrier(0);

        // ---- in-wave gates: z rows 0,1 = acc[0], acc[1] for col = lane ----
        const float z0 = acc[0] + bsv;
        const float z1 = acc[1] + bsv;
        float m0 = isC ? 2.0f * z0 : z0;
        float m1 = isC ? 2.0f * z1 : z1;
        float sg0 = 1.0f / (1.0f + __expf(-m0));
        float sg1 = 1.0f / (1.0f + __expf(-m1));
        float av0 = isC ? fmaf(2.0f, sg0, -1.0f) : sg0;   // tanh for g==2
        float av1 = isC ? fmaf(2.0f, sg1, -1.0f) : sg1;
        const int lb = l & 60;                             // gate-group base
        float iv0 = __shfl(av0, lb),     iv1 = __shfl(av1, lb);
        float fv0 = __shfl(av0, lb + 1), fv1 = __shfl(av1, lb + 1);
        float gv0 = __shfl(av0, lb + 2), gv1 = __shfl(av1, lb + 2);
        float ov0 = __shfl(av0, lb + 3), ov1 = __shfl(av1, lb + 3);
        cst0 = fmaf(fv0, cst0, iv0 * gv0);
        cst1 = fmaf(fv1, cst1, iv1 * gv1);
        const float th0 = 1.0f - 2.0f / (__expf(2.0f * cst0) + 1.0f);
        const float th1 = 1.0f - 2.0f / (__expf(2.0f * cst1) + 1.0f);
        const float h0 = ov0 * th0;
        const float h1 = ov1 * th1;
        const float hno0 = __shfl(h0, lb + 4);             // h of next h-col
        const float hno1 = __shfl(h1, lb + 4);

        if (s == TSTEPS - 1) {
            if ((l & 3) == 0 && l < 16) {
                out[(2 * pg)     * HDIM + cg * 64 + jj] = (h0 >= 0.f) ? h0 : 0.3f * h0;
                out[(2 * pg + 1) * HDIM + cg * 64 + jj] = (h1 >= 0.f) ? h1 : 0.3f * h1;
            }
        } else {
            if ((l & 3) == 0 && l < 16) {                  // own-h (f16)
                ((_Float16*)&xh[ncp][0][0])[64 + jj] = (_Float16)h0;
                ((_Float16*)&xh[ncp][1][0])[64 + jj] = (_Float16)h1;
            }
            if (l == 0 || l == 8) {                        // tagged publish
                const int ps = 2 * w + (l >> 3);
                const unsigned long long tg =
                    ((unsigned long long)(unsigned)(s + 1)) << 32;
                unsigned long long* const pb0 =
                    ex2 + ((size_t)((pg * 4 + cg) * 2 + ncp) * 2 + 0) * 32 + ps;
                unsigned long long* const pb1 =
                    ex2 + ((size_t)((pg * 4 + cg) * 2 + ncp) * 2 + 1) * 32 + ps;
                __hip_atomic_store(pb0, tg | pack2(h0, hno0),
                                   __ATOMIC_RELAXED, __HIP_MEMORY_SCOPE_AGENT);
                __hip_atomic_store(pb1, tg | pack2(h1, hno1),
                                   __ATOMIC_RELAXED, __HIP_MEMORY_SCOPE_AGENT);
            }
            if (stg) xh[ncp][srr][sdd] = pack2(xnext.x, xnext.y);
        }
        __syncthreads();                                   // B3
    }
}

// ---- fallback (needs no ws): round-1 kernel ----
__global__ __launch_bounds__(HDIM) void lstm_fused(
    const float* __restrict__ inputs, const float* __restrict__ wk,
    const float* __restrict__ wr, const float* __restrict__ bias,
    float* __restrict__ out)
{
    const int b = blockIdx.x;
    const int t = threadIdx.x;
    __shared__ float hs[2][HDIM];
    __shared__ float xs[2][FDIM];
    const float* __restrict__ xin = inputs + (size_t)b * TSTEPS * FDIM;
    float c = 0.0f;
    hs[0][t] = 0.0f;
    if (t < FDIM) xs[0][t] = xin[t];
    const float bi = bias[t];
    const float bf = bias[HDIM + t];
    const float bc = bias[2 * HDIM + t];
    const float bo = bias[3 * HDIM + t];
    __syncthreads();
    int p = 0;
    for (int step = 0; step < TSTEPS; ++step) {
        float zi = bi, zf = bf, zc = bc, zo = bo;
        const float* xsp = xs[p];
        const float* hsp = hs[p];
        #pragma unroll 8
        for (int f = 0; f < FDIM; ++f) {
            const float xv = xsp[f];
            const float* Kf = wk + f * G4 + t;
            zi = fmaf(xv, Kf[0], zi);
            zf = fmaf(xv, Kf[HDIM], zf);
            zc = fmaf(xv, Kf[2 * HDIM], zc);
            zo = fmaf(xv, Kf[3 * HDIM], zo);
        }
        #pragma unroll 8
        for (int k = 0; k < HDIM; ++k) {
            const float hv = hsp[k];
            const float* Rk = wr + k * G4 + t;
            zi = fmaf(hv, Rk[0], zi);
            zf = fmaf(hv, Rk[HDIM], zf);
            zc = fmaf(hv, Rk[2 * HDIM], zc);
            zo = fmaf(hv, Rk[3 * HDIM], zo);
        }
        const float ig = 1.0f / (1.0f + __expf(-zi));
        const float fg = 1.0f / (1.0f + __expf(-zf));
        const float gg = 1.0f - 2.0f / (__expf(2.0f * zc) + 1.0f);
        const float og = 1.0f / (1.0f + __expf(-zo));
        c = fmaf(fg, c, ig * gg);
        const float hn = og * (1.0f - 2.0f / (__expf(2.0f * c) + 1.0f));
        float xnext = 0.0f;
        if (t < FDIM && step + 1 < TSTEPS) xnext = xin[(step + 1) * FDIM + t];
        hs[p ^ 1][t] = hn;
        if (t < FDIM) xs[p ^ 1][t] = xnext;
        __syncthreads();
        p ^= 1;
    }
    const float h = hs[p][t];
    out[b * HDIM + t] = (h >= 0.0f) ? h : 0.3f * h;
}

extern "C" void kernel_launch(void* const* d_in, const int* in_sizes, int n_in,
                              void* d_out, int out_size, void* d_ws, size_t ws_size,
                              hipStream_t stream) {
    const float* inputs = (const float*)d_in[0];
    const float* wk     = (const float*)d_in[1];
    const float* wr     = (const float*)d_in[2];
    const float* bias   = (const float*)d_in[3];
    float* out          = (float*)d_out;

    if (ws_size >= (size_t)WS_NEED) {
        unsigned* w4s = (unsigned*)d_ws;
        unsigned long long* ex2 = (unsigned long long*)((char*)d_ws + EX_OFF);
        hipMemsetAsync(ex2, 0xFF, EX_BYTES, stream);   // all tags invalid
        int ndw = W4S_U4 * 4;
        pack_mfma<<<dim3((ndw + 255) / 256), dim3(256), 0, stream>>>(wk, wr, w4s);
        lstm_mfma<<<dim3(256), dim3(1024), 0, stream>>>(
            inputs, w4s, bias, ex2, out);
    } else {
        lstm_fused<<<dim3(BATCH), dim3(HDIM), 0, stream>>>(inputs, wk, wr, bias, out);
    }
}

// Round 9
// 2789.325 us; speedup vs baseline: 1.0124x; 1.0124x over previous
//
#include <hip/hip_runtime.h>

// LSTM last-h + LeakyReLU(0.3). B=128 T=1024 F=64 H=256.
// R26: R25 (passing MFMA design, 2823us) + three fixes:
//  (a) 16KB LDS pad (R22-proven guard-read materialization) -> 84.5KB
//      > 80KB -> 1 WG/CU guaranteed. R25's 68KB allowed 2 WGs/CU; the
//      greedy dispatcher packs 2 on some CUs and idles others
//      (Occupancy fell 47->38% with FEWER vgprs) -- prime suspect.
//  (b) the 8 gate quad-broadcast __shfl -> mov_dpp quad_perm (VALU pipe,
//      exact lane semantics): DS ops 10 -> 2 per thread per step. The
//      4 gates of an h-col are exactly a lane quad (c = 4j+g).
//  (c) split accumulators: accA (LDS chunks 0-3, pre-barrier) and accB
//      (AGPR chunks 4-9, post-barrier), summed in the gate math --
//      breaks the ~200cy serial cross-barrier MFMA dependency chain.
// Structure otherwise R25: z[2x256] = xh[2x320] @ W[320x256] as 10
// v_mfma_f32_16x16x32_f16 per wave; B chunks 0-3 LDS, 4-9 AGPR;
// in-wave gates; R17-proven tagged-uint64 exchange; 2 barriers/step.

#define BATCH   128
#define TSTEPS  1024
#define FDIM    64
#define HDIM    256
#define G4      1024
#define NCHUNK  10
#define W4S_U4     (4 * NCHUNK * 1024)           // 40960 uint4
#define W4S_BYTES  (W4S_U4 * 16)                 // 655360
#define EX_OFF     W4S_BYTES
#define EX_SLOTS   (64 * 4 * 2 * 2 * 32)         // 32768 uint64 slots
#define EX_BYTES   (EX_SLOTS * 8)                // 262144
#define WS_NEED    (EX_OFF + EX_BYTES)           // 917504 (unchanged)

typedef unsigned u32x4 __attribute__((ext_vector_type(4)));
typedef float    f32x4 __attribute__((ext_vector_type(4)));

__device__ __forceinline__ unsigned pack2(float a, float b) {
    union { _Float16 h[2]; unsigned u; } c;
    c.h[0] = (_Float16)a; c.h[1] = (_Float16)b; return c.u;
}

// quad broadcast via DPP: every lane of a 4-lane quad gets quad-lane k.
#define QBCAST(x, k) \
    __int_as_float(__builtin_amdgcn_mov_dpp(__float_as_int(x), \
                   (k) * 0x55, 0xF, 0xF, false))

// B-fragment pack: w4s[cg][c][w][l] (uint4) holds B[k,col] f16 pairs with
// col = 16w + (l&15) -> (j = 4w + ((l&15)>>2), g = l&3), gcol = g*256+cg*64+j
// k = c*32 + ((l>>4)&3)*8 + 2d + s2   (matrix-core B layout, 16x16x32)
__global__ void pack_mfma(const float* __restrict__ wk,
                          const float* __restrict__ wr,
                          unsigned* __restrict__ w4s) {
    int idx = blockIdx.x * blockDim.x + threadIdx.x;
    if (idx >= W4S_U4 * 4) return;
    int u4 = idx >> 2, d = idx & 3;
    int l  = u4 & 63;
    int w  = (u4 >> 6) & 15;
    int c  = (u4 >> 10) % NCHUNK;
    int cg = u4 / (NCHUNK * 1024);
    int j  = 4 * w + ((l & 15) >> 2);
    int g  = l & 3;
    int gcol = g * 256 + cg * 64 + j;
    int kb = c * 32 + ((l >> 4) & 3) * 8 + 2 * d;
    float v[2];
    #pragma unroll
    for (int s2 = 0; s2 < 2; ++s2) {
        int kp = kb + s2;
        float val;
        if (kp < 64)       val = wk[kp * G4 + gcol];
        else if (kp < 128) val = wr[(cg * 64 + (kp - 64)) * G4 + gcol];
        else {
            int m = 1 + ((kp - 128) >> 6);
            val = wr[(((cg + m) & 3) * 64 + ((kp - 128) & 63)) * G4 + gcol];
        }
        v[s2] = val;
    }
    w4s[idx] = pack2(v[0], v[1]);
}

#define MFMA_LDS(c, ACC) do { \
    u32x4 av_ = Apl[4 * (c)]; \
    u32x4 bv_ = Bp[(c) << 10]; \
    asm volatile("v_mfma_f32_16x16x32_f16 %0, %1, %2, %0" \
                 : "+v"(ACC) : "v"(av_), "v"(bv_)); } while (0)

#define MFMA_REG(c, W, ACC) do { \
    u32x4 av_ = Apl[4 * (c)]; \
    asm volatile("v_mfma_f32_16x16x32_f16 %0, %1, %2, %0" \
                 : "+v"(ACC) : "v"(av_), "a"(W)); } while (0)

__global__ __launch_bounds__(1024) void lstm_mfma(
    const float* __restrict__ inputs,
    const unsigned* __restrict__ w4s,
    const float* __restrict__ bias,
    unsigned long long* __restrict__ ex2,
    float* __restrict__ out)
{
    __shared__ u32x4 ldsB[4 * 1024];                    // 64 KB: B chunks 0-3
    __shared__ __align__(16) unsigned xh[2][2][160];    // 2.5 KB
    __shared__ unsigned ldsPad[4096];                   // 16 KB occupancy pad

    const int bid = blockIdx.x;
    const int pg  = bid & 63;                  // batch rows 2pg, 2pg+1
    const int cg  = bid >> 6;                  // col-group 0..3
    const int tid = threadIdx.x;
    const int l   = tid & 63;
    const int w   = tid >> 6;

    const u32x4* __restrict__ Wcg = (const u32x4*)w4s + (size_t)cg * (NCHUNK * 1024);

    // LDS fill: B chunks 0-3 (linear copy; layout already fragment-packed)
    for (int i = tid; i < 4 * 1024; i += 1024) ldsB[i] = Wcg[i];

    // B chunks 4-9 -> AGPRs (24 regs), loaded once, pinned in "a" class
    u32x4 Wr0 = Wcg[4 * 1024 + tid]; asm volatile("" : "+a"(Wr0));
    u32x4 Wr1 = Wcg[5 * 1024 + tid]; asm volatile("" : "+a"(Wr1));
    u32x4 Wr2 = Wcg[6 * 1024 + tid]; asm volatile("" : "+a"(Wr2));
    u32x4 Wr3 = Wcg[7 * 1024 + tid]; asm volatile("" : "+a"(Wr3));
    u32x4 Wr4 = Wcg[8 * 1024 + tid]; asm volatile("" : "+a"(Wr4));
    u32x4 Wr5 = Wcg[9 * 1024 + tid]; asm volatile("" : "+a"(Wr5));

    const float* __restrict__ xr0 = inputs + (size_t)(2 * pg)     * TSTEPS * FDIM;
    const float* __restrict__ xr1 = inputs + (size_t)(2 * pg + 1) * TSTEPS * FDIM;

    // init xh[0]: dw 0..31 = x_0 (f16 pairs), 32..159 = h_0 = 0
    if (tid < 64) {
        int r = tid >> 5, dd = tid & 31;
        float2 x2 = ((const float2*)(r ? xr1 : xr0))[dd];
        xh[0][r][dd] = pack2(x2.x, x2.y);
    } else if (tid < 320) {
        int t2 = tid - 64;
        xh[0][t2 >> 7][32 + (t2 & 127)] = 0u;
    }

    // gate identity per lane (lanes 0..15 meaningful)
    const int  jj  = 4 * w + ((l & 15) >> 2);
    const int  g   = l & 3;
    const float bsv = bias[g * 256 + cg * 64 + jj];
    const bool isC  = (g == 2);                 // c-gate uses tanh

    // Occupancy-pad keep-alive (R22-proven): read under a bias-dependent
    // never-true unprovable guard feeding a global store -> not DCE-able.
    // Forces LDS_Block_Size ~84.5KB > 80KB -> 1 WG/CU at dispatch.
    if (bsv > 1e30f) out[tid] = (float)ldsPad[tid & 4095];

    // A-fragment bases (NO restrict: xh is rewritten through xh[][][]).
    // row = l&1 (rows 2-15 fed duplicates; their D rows unread),
    // kgroup = l>>4.
    const char* xb = (const char*)&xh[0][0][0];
    const u32x4* A0 =
        (const u32x4*)(xb + ((l & 1) * 160) * 4 + ((l >> 4) & 3) * 16);
    const u32x4* A1 =
        (const u32x4*)(xb + ((2 + (l & 1)) * 160) * 4 + ((l >> 4) & 3) * 16);
    const u32x4* Bp = ldsB + tid;               // NO restrict

    // gather: lanes 16..27 of every wave (16*12 = 192 = 3 partners x 64)
    const int  gl   = (l >= 16 && l < 28) ? (l - 16) : 0;
    const int  gidx = w * 12 + gl;
    const int  mi   = gidx >> 6, wi_ = gidx & 63;
    const int  grr  = wi_ >> 5, gdw = wi_ & 31;
    const int  cgp  = (cg + mi + 1) & 3;
    unsigned long long* const srcE =
        ex2 + ((size_t)((pg * 4 + cgp) * 2 + 0) * 2 + grr) * 32 + gdw;
    unsigned long long* const srcO =
        ex2 + ((size_t)((pg * 4 + cgp) * 2 + 1) * 2 + grr) * 32 + gdw;
    unsigned* const dstE = &xh[0][grr][64 + mi * 32 + gdw];
    unsigned* const dstO = &xh[1][grr][64 + mi * 32 + gdw];

    // stagers: lanes 28..31 of every wave (16*4 = 64 = 2 rows x 32 dwords)
    const int  sl  = (l >= 28 && l < 32) ? (l - 28) : 0;
    const int  sx  = w * 4 + sl;
    const int  srr = sx >> 5, sdd = sx & 31;
    const float2* __restrict__ xsp = (const float2*)(srr ? xr1 : xr0) + sdd;

    float cst0 = 0.0f, cst1 = 0.0f;
    __syncthreads();

    for (int s = 0; s < TSTEPS; ++s) {
        const int par = s & 1, ncp = par ^ 1;
        const u32x4* Apl = par ? A1 : A0;

        // speculative poll issue (flies under chunks 0-3)
        const bool gath = (l >= 16) && (l < 28) && (s > 0);
        unsigned long long* const gsrc = par ? srcO : srcE;
        unsigned long long pv = 0;
        if (gath) pv = __hip_atomic_load(gsrc, __ATOMIC_RELAXED,
                                         __HIP_MEMORY_SCOPE_AGENT);

        // x_{s+1} prefetch
        const bool stg = (l >= 28) && (l < 32) && (s + 1 < TSTEPS);
        float2 xnext = make_float2(0.f, 0.f);
        if (stg) xnext = xsp[(s + 1) * 32];

        f32x4 accA = {0.0f, 0.0f, 0.0f, 0.0f};
        f32x4 accB = {0.0f, 0.0f, 0.0f, 0.0f};
        // VALU write -> MFMA SrcC hazard guard (inline-asm MFMAs get no
        // automatic hazard handling), and pins init before the cluster.
        asm volatile("s_nop 1" : "+v"(accA), "+v"(accB));

        // chunks 0-3: x + own-h (B from LDS) -> accA
        MFMA_LDS(0, accA); MFMA_LDS(1, accA);
        MFMA_LDS(2, accA); MFMA_LDS(3, accA);

        // gather completion after own-work: B1 at max(D_early, RTT-rem)
        if (gath) {
            int it = 0;
            while ((unsigned)(pv >> 32) != (unsigned)s && ++it < (1 << 22))
                pv = __hip_atomic_load(gsrc, __ATOMIC_RELAXED,
                                       __HIP_MEMORY_SCOPE_AGENT);
            unsigned gv = ((unsigned)(pv >> 32) == (unsigned)s) ? (unsigned)pv : 0u;
            *(par ? dstO : dstE) = gv;
        }
        __syncthreads();                                   // B1

        // chunks 4-9: partner-h (B from AGPR) -> accB (independent chain)
        MFMA_REG(4, Wr0, accB); MFMA_REG(5, Wr1, accB); MFMA_REG(6, Wr2, accB);
        MFMA_REG(7, Wr3, accB); MFMA_REG(8, Wr4, accB); MFMA_REG(9, Wr5, accB);

        // SW hazard guard: MFMA -> VALU reads of accA/accB. The register
        // dependencies force every subsequent acc read AFTER these nops.
        asm volatile("s_nop 7\n\ts_nop 7\n\ts_nop 7" : "+v"(accB), "+v"(accA));
        __builtin_amdgcn_sched_barrier(0);

        // ---- in-wave gates: z rows 0,1 for col = lane&15 ----
        const float z0 = accA[0] + accB[0] + bsv;
        const float z1 = accA[1] + accB[1] + bsv;
        float m0 = isC ? 2.0f * z0 : z0;
        float m1 = isC ? 2.0f * z1 : z1;
        float sg0 = 1.0f / (1.0f + __expf(-m0));
        float sg1 = 1.0f / (1.0f + __expf(-m1));
        float av0 = isC ? fmaf(2.0f, sg0, -1.0f) : sg0;   // tanh for g==2
        float av1 = isC ? fmaf(2.0f, sg1, -1.0f) : sg1;
        // gate quad-broadcasts on the VALU pipe (DPP), not DS:
        float iv0 = QBCAST(av0, 0), iv1 = QBCAST(av1, 0);
        float fv0 = QBCAST(av0, 1), fv1 = QBCAST(av1, 1);
        float gv0 = QBCAST(av0, 2), gv1 = QBCAST(av1, 2);
        float ov0 = QBCAST(av0, 3), ov1 = QBCAST(av1, 3);
        cst0 = fmaf(fv0, cst0, iv0 * gv0);
        cst1 = fmaf(fv1, cst1, iv1 * gv1);
        const float th0 = 1.0f - 2.0f / (__expf(2.0f * cst0) + 1.0f);
        const float th1 = 1.0f - 2.0f / (__expf(2.0f * cst1) + 1.0f);
        const float h0 = ov0 * th0;                        // quad-uniform
        const float h1 = ov1 * th1;
        const int lb = l & 60;
        const float hno0 = __shfl(h0, lb + 4);             // next h-col
        const float hno1 = __shfl(h1, lb + 4);

        if (s == TSTEPS - 1) {
            if ((l & 3) == 0 && l < 16) {
                out[(2 * pg)     * HDIM + cg * 64 + jj] = (h0 >= 0.f) ? h0 : 0.3f * h0;
                out[(2 * pg + 1) * HDIM + cg * 64 + jj] = (h1 >= 0.f) ? h1 : 0.3f * h1;
            }
        } else {
            if ((l & 3) == 0 && l < 16) {                  // own-h (f16)
                ((_Float16*)&xh[ncp][0][0])[64 + jj] = (_Float16)h0;
                ((_Float16*)&xh[ncp][1][0])[64 + jj] = (_Float16)h1;
            }
            if (l == 0 || l == 8) {                        // tagged publish
                const int ps = 2 * w + (l >> 3);
                const unsigned long long tg =
                    ((unsigned long long)(unsigned)(s + 1)) << 32;
                unsigned long long* const pb0 =
                    ex2 + ((size_t)((pg * 4 + cg) * 2 + ncp) * 2 + 0) * 32 + ps;
                unsigned long long* const pb1 =
                    ex2 + ((size_t)((pg * 4 + cg) * 2 + ncp) * 2 + 1) * 32 + ps;
                __hip_atomic_store(pb0, tg | pack2(h0, hno0),
                                   __ATOMIC_RELAXED, __HIP_MEMORY_SCOPE_AGENT);
                __hip_atomic_store(pb1, tg | pack2(h1, hno1),
                                   __ATOMIC_RELAXED, __HIP_MEMORY_SCOPE_AGENT);
            }
            if (stg) xh[ncp][srr][sdd] = pack2(xnext.x, xnext.y);
        }
        __syncthreads();                                   // B3
    }
}

// ---- fallback (needs no ws): round-1 kernel ----
__global__ __launch_bounds__(HDIM) void lstm_fused(
    const float* __restrict__ inputs, const float* __restrict__ wk,
    const float* __restrict__ wr, const float* __restrict__ bias,
    float* __restrict__ out)
{
    const int b = blockIdx.x;
    const int t = threadIdx.x;
    __shared__ float hs[2][HDIM];
    __shared__ float xs[2][FDIM];
    const float* __restrict__ xin = inputs + (size_t)b * TSTEPS * FDIM;
    float c = 0.0f;
    hs[0][t] = 0.0f;
    if (t < FDIM) xs[0][t] = xin[t];
    const float bi = bias[t];
    const float bf = bias[HDIM + t];
    const float bc = bias[2 * HDIM + t];
    const float bo = bias[3 * HDIM + t];
    __syncthreads();
    int p = 0;
    for (int step = 0; step < TSTEPS; ++step) {
        float zi = bi, zf = bf, zc = bc, zo = bo;
        const float* xsp = xs[p];
        const float* hsp = hs[p];
        #pragma unroll 8
        for (int f = 0; f < FDIM; ++f) {
            const float xv = xsp[f];
            const float* Kf = wk + f * G4 + t;
            zi = fmaf(xv, Kf[0], zi);
            zf = fmaf(xv, Kf[HDIM], zf);
            zc = fmaf(xv, Kf[2 * HDIM], zc);
            zo = fmaf(xv, Kf[3 * HDIM], zo);
        }
        #pragma unroll 8
        for (int k = 0; k < HDIM; ++k) {
            const float hv = hsp[k];
            const float* Rk = wr + k * G4 + t;
            zi = fmaf(hv, Rk[0], zi);
            zf = fmaf(hv, Rk[HDIM], zf);
            zc = fmaf(hv, Rk[2 * HDIM], zc);
            zo = fmaf(hv, Rk[3 * HDIM], zo);
        }
        const float ig = 1.0f / (1.0f + __expf(-zi));
        const float fg = 1.0f / (1.0f + __expf(-zf));
        const float gg = 1.0f - 2.0f / (__expf(2.0f * zc) + 1.0f);
        const float og = 1.0f / (1.0f + __expf(-zo));
        c = fmaf(fg, c, ig * gg);
        const float hn = og * (1.0f - 2.0f / (__expf(2.0f * c) + 1.0f));
        float xnext = 0.0f;
        if (t < FDIM && step + 1 < TSTEPS) xnext = xin[(step + 1) * FDIM + t];
        hs[p ^ 1][t] = hn;
        if (t < FDIM) xs[p ^ 1][t] = xnext;
        __syncthreads();
        p ^= 1;
    }
    const float h = hs[p][t];
    out[b * HDIM + t] = (h >= 0.0f) ? h : 0.3f * h;
}

extern "C" void kernel_launch(void* const* d_in, const int* in_sizes, int n_in,
                              void* d_out, int out_size, void* d_ws, size_t ws_size,
                              hipStream_t stream) {
    const float* inputs = (const float*)d_in[0];
    const float* wk     = (const float*)d_in[1];
    const float* wr     = (const float*)d_in[2];
    const float* bias   = (const float*)d_in[3];
    float* out          = (float*)d_out;

    if (ws_size >= (size_t)WS_NEED) {
        unsigned* w4s = (unsigned*)d_ws;
        unsigned long long* ex2 = (unsigned long long*)((char*)d_ws + EX_OFF);
        hipMemsetAsync(ex2, 0xFF, EX_BYTES, stream);   // all tags invalid
        int ndw = W4S_U4 * 4;
        pack_mfma<<<dim3((ndw + 255) / 256), dim3(256), 0, stream>>>(wk, wr, w4s);
        lstm_mfma<<<dim3(256), dim3(1024), 0, stream>>>(
            inputs, w4s, bias, ex2, out);
    } else {
        lstm_fused<<<dim3(BATCH), dim3(HDIM), 0, stream>>>(inputs, wk, wr, bias, out);
    }
}

// Round 10
// 2786.611 us; speedup vs baseline: 1.0134x; 1.0010x over previous
//
#include <hip/hip_runtime.h>

// LSTM last-h + LeakyReLU(0.3). B=128 T=1024 F=64 H=256.
// R27: R26 with a STRUCTURAL occupancy forcer (single merged LDS array).
// R26 post-mortem: separate never-written ldsPad = undef loads -> whole
// array DCE'd; LDS stayed 68KB -> 2 WGs/CU packable; occupancy 39%
// (anomalous), dur 2789us. DPP-gates + split-acc moved ~1% -> DS/chain
// not binding; packing imbalance is the remaining suspect (R17: >=119KB
// = 1 WG/CU = 4200cy/step with MORE compute; R25/R26 are the only 2-WG
// variants and the slow ones). Fix mirrors R22's success: ONE __shared__
// array whose head is genuinely read+written (B chunks + xh) and whose
// declared size 84480B > 80KB; allocation is all-or-nothing, cannot be
// shrunk -> hardware cannot co-schedule a 2nd WG.
// Structure otherwise R26: z[2x256] = xh[2x320] @ W[320x256] as 10
// v_mfma_f32_16x16x32_f16 per wave; B chunks 0-3 LDS, 4-9 AGPR;
// in-wave gates w/ DPP quad-broadcast; split accA/accB; R17 tagged
// exchange; 2 barriers/step.

#define BATCH   128
#define TSTEPS  1024
#define FDIM    64
#define HDIM    256
#define G4      1024
#define NCHUNK  10
#define W4S_U4     (4 * NCHUNK * 1024)           // 40960 uint4
#define W4S_BYTES  (W4S_U4 * 16)                 // 655360
#define EX_OFF     W4S_BYTES
#define EX_SLOTS   (64 * 4 * 2 * 2 * 32)         // 32768 uint64 slots
#define EX_BYTES   (EX_SLOTS * 8)                // 262144
#define WS_NEED    (EX_OFF + EX_BYTES)           // 917504 (unchanged)

#define LDS_TOT_U4 5280                          // 84480 B > 81920 -> 1 WG/CU

typedef unsigned u32x4 __attribute__((ext_vector_type(4)));
typedef float    f32x4 __attribute__((ext_vector_type(4)));

__device__ __forceinline__ unsigned pack2(float a, float b) {
    union { _Float16 h[2]; unsigned u; } c;
    c.h[0] = (_Float16)a; c.h[1] = (_Float16)b; return c.u;
}

// quad broadcast via DPP: every lane of a 4-lane quad gets quad-lane k.
#define QBCAST(x, k) \
    __int_as_float(__builtin_amdgcn_mov_dpp(__float_as_int(x), \
                   (k) * 0x55, 0xF, 0xF, false))

// B-fragment pack: w4s[cg][c][w][l] (uint4) holds B[k,col] f16 pairs with
// col = 16w + (l&15) -> (j = 4w + ((l&15)>>2), g = l&3), gcol = g*256+cg*64+j
// k = c*32 + ((l>>4)&3)*8 + 2d + s2   (matrix-core B layout, 16x16x32)
__global__ void pack_mfma(const float* __restrict__ wk,
                          const float* __restrict__ wr,
                          unsigned* __restrict__ w4s) {
    int idx = blockIdx.x * blockDim.x + threadIdx.x;
    if (idx >= W4S_U4 * 4) return;
    int u4 = idx >> 2, d = idx & 3;
    int l  = u4 & 63;
    int w  = (u4 >> 6) & 15;
    int c  = (u4 >> 10) % NCHUNK;
    int cg = u4 / (NCHUNK * 1024);
    int j  = 4 * w + ((l & 15) >> 2);
    int g  = l & 3;
    int gcol = g * 256 + cg * 64 + j;
    int kb = c * 32 + ((l >> 4) & 3) * 8 + 2 * d;
    float v[2];
    #pragma unroll
    for (int s2 = 0; s2 < 2; ++s2) {
        int kp = kb + s2;
        float val;
        if (kp < 64)       val = wk[kp * G4 + gcol];
        else if (kp < 128) val = wr[(cg * 64 + (kp - 64)) * G4 + gcol];
        else {
            int m = 1 + ((kp - 128) >> 6);
            val = wr[(((cg + m) & 3) * 64 + ((kp - 128) & 63)) * G4 + gcol];
        }
        v[s2] = val;
    }
    w4s[idx] = pack2(v[0], v[1]);
}

#define MFMA_LDS(c, ACC) do { \
    u32x4 av_ = Apl[4 * (c)]; \
    u32x4 bv_ = Bp[(c) << 10]; \
    asm volatile("v_mfma_f32_16x16x32_f16 %0, %1, %2, %0" \
                 : "+v"(ACC) : "v"(av_), "v"(bv_)); } while (0)

#define MFMA_REG(c, W, ACC) do { \
    u32x4 av_ = Apl[4 * (c)]; \
    asm volatile("v_mfma_f32_16x16x32_f16 %0, %1, %2, %0" \
                 : "+v"(ACC) : "v"(av_), "a"(W)); } while (0)

__global__ __launch_bounds__(1024) void lstm_mfma(
    const float* __restrict__ inputs,
    const unsigned* __restrict__ w4s,
    const float* __restrict__ bias,
    unsigned long long* __restrict__ ex2,
    float* __restrict__ out)
{
    // ONE merged LDS block (84480 B): allocation is all-or-nothing, so
    // the declared size forces 1 WG/CU at dispatch.
    //   [0    .. 4095]  B chunks 0-3 (u32x4)          -- written + read
    //   [4096 .. 4415]  xh[2][2][160] dwords          -- written + read
    //   [4416 .. 5279]  occupancy tail (never touched; part of the same
    //                   allocation, cannot be shrunk)
    __shared__ u32x4 ldsAll[LDS_TOT_U4];
    u32x4* const ldsB = ldsAll;
    typedef unsigned xh_row_t[2][160];
    xh_row_t* const xh = reinterpret_cast<xh_row_t*>((unsigned*)(ldsAll + 4096));

    const int bid = blockIdx.x;
    const int pg  = bid & 63;                  // batch rows 2pg, 2pg+1
    const int cg  = bid >> 6;                  // col-group 0..3
    const int tid = threadIdx.x;
    const int l   = tid & 63;
    const int w   = tid >> 6;

    const u32x4* __restrict__ Wcg = (const u32x4*)w4s + (size_t)cg * (NCHUNK * 1024);

    // LDS fill: B chunks 0-3 (linear copy; layout already fragment-packed)
    for (int i = tid; i < 4 * 1024; i += 1024) ldsB[i] = Wcg[i];

    // B chunks 4-9 -> AGPRs (24 regs), loaded once, pinned in "a" class
    u32x4 Wr0 = Wcg[4 * 1024 + tid]; asm volatile("" : "+a"(Wr0));
    u32x4 Wr1 = Wcg[5 * 1024 + tid]; asm volatile("" : "+a"(Wr1));
    u32x4 Wr2 = Wcg[6 * 1024 + tid]; asm volatile("" : "+a"(Wr2));
    u32x4 Wr3 = Wcg[7 * 1024 + tid]; asm volatile("" : "+a"(Wr3));
    u32x4 Wr4 = Wcg[8 * 1024 + tid]; asm volatile("" : "+a"(Wr4));
    u32x4 Wr5 = Wcg[9 * 1024 + tid]; asm volatile("" : "+a"(Wr5));

    const float* __restrict__ xr0 = inputs + (size_t)(2 * pg)     * TSTEPS * FDIM;
    const float* __restrict__ xr1 = inputs + (size_t)(2 * pg + 1) * TSTEPS * FDIM;

    // init xh[0]: dw 0..31 = x_0 (f16 pairs), 32..159 = h_0 = 0
    if (tid < 64) {
        int r = tid >> 5, dd = tid & 31;
        float2 x2 = ((const float2*)(r ? xr1 : xr0))[dd];
        xh[0][r][dd] = pack2(x2.x, x2.y);
    } else if (tid < 320) {
        int t2 = tid - 64;
        xh[0][t2 >> 7][32 + (t2 & 127)] = 0u;
    }

    // gate identity per lane (lanes 0..15 meaningful)
    const int  jj  = 4 * w + ((l & 15) >> 2);
    const int  g   = l & 3;
    const float bsv = bias[g * 256 + cg * 64 + jj];
    const bool isC  = (g == 2);                 // c-gate uses tanh

    // A-fragment bases (NO restrict: xh is rewritten through xh[][][]).
    // row = l&1 (rows 2-15 fed duplicates; their D rows unread),
    // kgroup = l>>4.
    const char* xb = (const char*)&xh[0][0][0];
    const u32x4* A0 =
        (const u32x4*)(xb + ((l & 1) * 160) * 4 + ((l >> 4) & 3) * 16);
    const u32x4* A1 =
        (const u32x4*)(xb + ((2 + (l & 1)) * 160) * 4 + ((l >> 4) & 3) * 16);
    const u32x4* Bp = ldsB + tid;               // NO restrict

    // gather: lanes 16..27 of every wave (16*12 = 192 = 3 partners x 64)
    const int  gl   = (l >= 16 && l < 28) ? (l - 16) : 0;
    const int  gidx = w * 12 + gl;
    const int  mi   = gidx >> 6, wi_ = gidx & 63;
    const int  grr  = wi_ >> 5, gdw = wi_ & 31;
    const int  cgp  = (cg + mi + 1) & 3;
    unsigned long long* const srcE =
        ex2 + ((size_t)((pg * 4 + cgp) * 2 + 0) * 2 + grr) * 32 + gdw;
    unsigned long long* const srcO =
        ex2 + ((size_t)((pg * 4 + cgp) * 2 + 1) * 2 + grr) * 32 + gdw;
    unsigned* const dstE = &xh[0][grr][64 + mi * 32 + gdw];
    unsigned* const dstO = &xh[1][grr][64 + mi * 32 + gdw];

    // stagers: lanes 28..31 of every wave (16*4 = 64 = 2 rows x 32 dwords)
    const int  sl  = (l >= 28 && l < 32) ? (l - 28) : 0;
    const int  sx  = w * 4 + sl;
    const int  srr = sx >> 5, sdd = sx & 31;
    const float2* __restrict__ xsp = (const float2*)(srr ? xr1 : xr0) + sdd;

    float cst0 = 0.0f, cst1 = 0.0f;
    __syncthreads();

    for (int s = 0; s < TSTEPS; ++s) {
        const int par = s & 1, ncp = par ^ 1;
        const u32x4* Apl = par ? A1 : A0;

        // speculative poll issue (flies under chunks 0-3)
        const bool gath = (l >= 16) && (l < 28) && (s > 0);
        unsigned long long* const gsrc = par ? srcO : srcE;
        unsigned long long pv = 0;
        if (gath) pv = __hip_atomic_load(gsrc, __ATOMIC_RELAXED,
                                         __HIP_MEMORY_SCOPE_AGENT);

        // x_{s+1} prefetch
        const bool stg = (l >= 28) && (l < 32) && (s + 1 < TSTEPS);
        float2 xnext = make_float2(0.f, 0.f);
        if (stg) xnext = xsp[(s + 1) * 32];

        f32x4 accA = {0.0f, 0.0f, 0.0f, 0.0f};
        f32x4 accB = {0.0f, 0.0f, 0.0f, 0.0f};
        // VALU write -> MFMA SrcC hazard guard (inline-asm MFMAs get no
        // automatic hazard handling), and pins init before the cluster.
        asm volatile("s_nop 1" : "+v"(accA), "+v"(accB));

        // chunks 0-3: x + own-h (B from LDS) -> accA
        MFMA_LDS(0, accA); MFMA_LDS(1, accA);
        MFMA_LDS(2, accA); MFMA_LDS(3, accA);

        // gather completion after own-work: B1 at max(D_early, RTT-rem)
        if (gath) {
            int it = 0;
            while ((unsigned)(pv >> 32) != (unsigned)s && ++it < (1 << 22))
                pv = __hip_atomic_load(gsrc, __ATOMIC_RELAXED,
                                       __HIP_MEMORY_SCOPE_AGENT);
            unsigned gv = ((unsigned)(pv >> 32) == (unsigned)s) ? (unsigned)pv : 0u;
            *(par ? dstO : dstE) = gv;
        }
        __syncthreads();                                   // B1

        // chunks 4-9: partner-h (B from AGPR) -> accB (independent chain)
        MFMA_REG(4, Wr0, accB); MFMA_REG(5, Wr1, accB); MFMA_REG(6, Wr2, accB);
        MFMA_REG(7, Wr3, accB); MFMA_REG(8, Wr4, accB); MFMA_REG(9, Wr5, accB);

        // SW hazard guard: MFMA -> VALU reads of accA/accB. The register
        // dependencies force every subsequent acc read AFTER these nops.
        asm volatile("s_nop 7\n\ts_nop 7\n\ts_nop 7" : "+v"(accB), "+v"(accA));
        __builtin_amdgcn_sched_barrier(0);

        // ---- in-wave gates: z rows 0,1 for col = lane&15 ----
        const float z0 = accA[0] + accB[0] + bsv;
        const float z1 = accA[1] + accB[1] + bsv;
        float m0 = isC ? 2.0f * z0 : z0;
        float m1 = isC ? 2.0f * z1 : z1;
        float sg0 = 1.0f / (1.0f + __expf(-m0));
        float sg1 = 1.0f / (1.0f + __expf(-m1));
        float av0 = isC ? fmaf(2.0f, sg0, -1.0f) : sg0;   // tanh for g==2
        float av1 = isC ? fmaf(2.0f, sg1, -1.0f) : sg1;
        // gate quad-broadcasts on the VALU pipe (DPP), not DS:
        float iv0 = QBCAST(av0, 0), iv1 = QBCAST(av1, 0);
        float fv0 = QBCAST(av0, 1), fv1 = QBCAST(av1, 1);
        float gv0 = QBCAST(av0, 2), gv1 = QBCAST(av1, 2);
        float ov0 = QBCAST(av0, 3), ov1 = QBCAST(av1, 3);
        cst0 = fmaf(fv0, cst0, iv0 * gv0);
        cst1 = fmaf(fv1, cst1, iv1 * gv1);
        const float th0 = 1.0f - 2.0f / (__expf(2.0f * cst0) + 1.0f);
        const float th1 = 1.0f - 2.0f / (__expf(2.0f * cst1) + 1.0f);
        const float h0 = ov0 * th0;                        // quad-uniform
        const float h1 = ov1 * th1;
        const int lb = l & 60;
        const float hno0 = __shfl(h0, lb + 4);             // next h-col
        const float hno1 = __shfl(h1, lb + 4);

        if (s == TSTEPS - 1) {
            if ((l & 3) == 0 && l < 16) {
                out[(2 * pg)     * HDIM + cg * 64 + jj] = (h0 >= 0.f) ? h0 : 0.3f * h0;
                out[(2 * pg + 1) * HDIM + cg * 64 + jj] = (h1 >= 0.f) ? h1 : 0.3f * h1;
            }
        } else {
            if ((l & 3) == 0 && l < 16) {                  // own-h (f16)
                ((_Float16*)&xh[ncp][0][0])[64 + jj] = (_Float16)h0;
                ((_Float16*)&xh[ncp][1][0])[64 + jj] = (_Float16)h1;
            }
            if (l == 0 || l == 8) {                        // tagged publish
                const int ps = 2 * w + (l >> 3);
                const unsigned long long tg =
                    ((unsigned long long)(unsigned)(s + 1)) << 32;
                unsigned long long* const pb0 =
                    ex2 + ((size_t)((pg * 4 + cg) * 2 + ncp) * 2 + 0) * 32 + ps;
                unsigned long long* const pb1 =
                    ex2 + ((size_t)((pg * 4 + cg) * 2 + ncp) * 2 + 1) * 32 + ps;
                __hip_atomic_store(pb0, tg | pack2(h0, hno0),
                                   __ATOMIC_RELAXED, __HIP_MEMORY_SCOPE_AGENT);
                __hip_atomic_store(pb1, tg | pack2(h1, hno1),
                                   __ATOMIC_RELAXED, __HIP_MEMORY_SCOPE_AGENT);
            }
            if (stg) xh[ncp][srr][sdd] = pack2(xnext.x, xnext.y);
        }
        __syncthreads();                                   // B3
    }
}

// ---- fallback (needs no ws): round-1 kernel ----
__global__ __launch_bounds__(HDIM) void lstm_fused(
    const float* __restrict__ inputs, const float* __restrict__ wk,
    const float* __restrict__ wr, const float* __restrict__ bias,
    float* __restrict__ out)
{
    const int b = blockIdx.x;
    const int t = threadIdx.x;
    __shared__ float hs[2][HDIM];
    __shared__ float xs[2][FDIM];
    const float* __restrict__ xin = inputs + (size_t)b * TSTEPS * FDIM;
    float c = 0.0f;
    hs[0][t] = 0.0f;
    if (t < FDIM) xs[0][t] = xin[t];
    const float bi = bias[t];
    const float bf = bias[HDIM + t];
    const float bc = bias[2 * HDIM + t];
    const float bo = bias[3 * HDIM + t];
    __syncthreads();
    int p = 0;
    for (int step = 0; step < TSTEPS; ++step) {
        float zi = bi, zf = bf, zc = bc, zo = bo;
        const float* xsp = xs[p];
        const float* hsp = hs[p];
        #pragma unroll 8
        for (int f = 0; f < FDIM; ++f) {
            const float xv = xsp[f];
            const float* Kf = wk + f * G4 + t;
            zi = fmaf(xv, Kf[0], zi);
            zf = fmaf(xv, Kf[HDIM], zf);
            zc = fmaf(xv, Kf[2 * HDIM], zc);
            zo = fmaf(xv, Kf[3 * HDIM], zo);
        }
        #pragma unroll 8
        for (int k = 0; k < HDIM; ++k) {
            const float hv = hsp[k];
            const float* Rk = wr + k * G4 + t;
            zi = fmaf(hv, Rk[0], zi);
            zf = fmaf(hv, Rk[HDIM], zf);
            zc = fmaf(hv, Rk[2 * HDIM], zc);
            zo = fmaf(hv, Rk[3 * HDIM], zo);
        }
        const float ig = 1.0f / (1.0f + __expf(-zi));
        const float fg = 1.0f / (1.0f + __expf(-zf));
        const float gg = 1.0f - 2.0f / (__expf(2.0f * zc) + 1.0f);
        const float og = 1.0f / (1.0f + __expf(-zo));
        c = fmaf(fg, c, ig * gg);
        const float hn = og * (1.0f - 2.0f / (__expf(2.0f * c) + 1.0f));
        float xnext = 0.0f;
        if (t < FDIM && step + 1 < TSTEPS) xnext = xin[(step + 1) * FDIM + t];
        hs[p ^ 1][t] = hn;
        if (t < FDIM) xs[p ^ 1][t] = xnext;
        __syncthreads();
        p ^= 1;
    }
    const float h = hs[p][t];
    out[b * HDIM + t] = (h >= 0.0f) ? h : 0.3f * h;
}

extern "C" void kernel_launch(void* const* d_in, const int* in_sizes, int n_in,
                              void* d_out, int out_size, void* d_ws, size_t ws_size,
                              hipStream_t stream) {
    const float* inputs = (const float*)d_in[0];
    const float* wk     = (const float*)d_in[1];
    const float* wr     = (const float*)d_in[2];
    const float* bias   = (const float*)d_in[3];
    float* out          = (float*)d_out;

    if (ws_size >= (size_t)WS_NEED) {
        unsigned* w4s = (unsigned*)d_ws;
        unsigned long long* ex2 = (unsigned long long*)((char*)d_ws + EX_OFF);
        hipMemsetAsync(ex2, 0xFF, EX_BYTES, stream);   // all tags invalid
        int ndw = W4S_U4 * 4;
        pack_mfma<<<dim3((ndw + 255) / 256), dim3(256), 0, stream>>>(wk, wr, w4s);
        lstm_mfma<<<dim3(256), dim3(1024), 0, stream>>>(
            inputs, w4s, bias, ex2, out);
    } else {
        lstm_fused<<<dim3(BATCH), dim3(HDIM), 0, stream>>>(inputs, wk, wr, bias, out);
    }
}